// Round 1
// baseline (3518.132 us; speedup 1.0000x reference)
//
#include <hip/hip_runtime.h>
#include <hip/hip_fp16.h>

#define B_   16
#define T_   4096
#define DIN  256
#define H_   128
#define G3   384   // 3*H

typedef _Float16 half2_t __attribute__((ext_vector_type(2)));

__device__ __forceinline__ float fdot2(unsigned int a, unsigned int b, float c) {
#if __has_builtin(__builtin_amdgcn_fdot2)
  return __builtin_amdgcn_fdot2(__builtin_bit_cast(half2_t, a),
                                __builtin_bit_cast(half2_t, b), c, false);
#else
  const __half2 ha = __builtin_bit_cast(__half2, a);
  const __half2 hb = __builtin_bit_cast(__half2, b);
  return c + __half2float(__low2half(ha)) * __half2float(__low2half(hb))
           + __half2float(__high2half(ha)) * __half2float(__high2half(hb));
#endif
}

__device__ __forceinline__ unsigned int pack2(float x, float y) {
  __half2 h = __floats2half2_rn(x, y);
  return __builtin_bit_cast(unsigned int, h);
}

__device__ __forceinline__ float fsigmoid(float x) {
  return 1.f / (1.f + __expf(-x));
}
__device__ __forceinline__ float ftanh(float x) {
  // 2*sigmoid(2x)-1 ; __expf(inf)->inf handled: x<<0 -> 2/inf-1 = -1
  return 2.f / (1.f + __expf(-2.f * x)) - 1.f;
}

// ---------------------------------------------------------------------------
// Kernel 1: gi[r, j] = f16( b_ih[j] + dot(x[r, :], w_ih[j, :]) )
// r in [0, B*T), j in [0, 384). Thread j holds w_ih row j as packed f16x2.
// ---------------------------------------------------------------------------
__global__ __launch_bounds__(384, 1) void gi_gemm(
    const float* __restrict__ x, const float* __restrict__ w_ih,
    const float* __restrict__ b_ih, __half* __restrict__ gi) {
  const int j = threadIdx.x;             // 0..383 : output gate-row
  const int rbase = blockIdx.x * 128;    // 128 x-rows per block

  unsigned int wreg[128];                // 256 halves = w_ih row j
  const float* wrow = w_ih + (size_t)j * DIN;
#pragma unroll
  for (int k = 0; k < 128; ++k) {
    float2 w2 = reinterpret_cast<const float2*>(wrow)[k];
    wreg[k] = pack2(w2.x, w2.y);
  }
  const float bias = b_ih[j];

  __shared__ alignas(16) unsigned int xs[16 * 128];  // 16 rows x 256 halves

  for (int c = 0; c < 8; ++c) {          // 8 chunks of 16 rows
    __syncthreads();                     // protect xs vs previous chunk reads
    const int row0 = rbase + c * 16;
    for (int i = j; i < 16 * 128; i += 384) {
      const int r = i >> 7, col = i & 127;
      float2 v = reinterpret_cast<const float2*>(x + (size_t)(row0 + r) * DIN)[col];
      xs[i] = pack2(v.x, v.y);
    }
    __syncthreads();
    for (int r = 0; r < 16; ++r) {
      float a0 = 0.f, a1 = 0.f, a2 = 0.f, a3 = 0.f;
      const uint4* hp = reinterpret_cast<const uint4*>(xs + r * 128);
#pragma unroll
      for (int k = 0; k < 32; ++k) {
        uint4 hv = hp[k];                // uniform addr -> LDS broadcast
        a0 = fdot2(wreg[4 * k + 0], hv.x, a0);
        a1 = fdot2(wreg[4 * k + 1], hv.y, a1);
        a2 = fdot2(wreg[4 * k + 2], hv.z, a2);
        a3 = fdot2(wreg[4 * k + 3], hv.w, a3);
      }
      const float acc = bias + ((a0 + a1) + (a2 + a3));
      gi[(size_t)(row0 + r) * G3 + j] = __float2half(acc);
    }
  }
}

// ---------------------------------------------------------------------------
// Kernel 2: sequential GRU scan. One block per batch element (16 blocks).
// Thread j (0..383) holds w_hh row j in registers (f16x2). h lives in LDS
// as f16 (broadcast reads). Threads 0..127 additionally compute the gates.
// Writes GRU hidden states (f32) to out[b, t, :].
// ---------------------------------------------------------------------------
__global__ __launch_bounds__(384, 1) void gru_scan(
    const __half* __restrict__ gi, const float* __restrict__ w_hh,
    const float* __restrict__ b_hh, float* __restrict__ out) {
  const int b = blockIdx.x;
  const int j = threadIdx.x;

  unsigned int wreg[64];                 // 128 halves = w_hh row j
  const float* wrow = w_hh + (size_t)j * H_;
#pragma unroll
  for (int k = 0; k < 64; ++k) {
    float2 w2 = reinterpret_cast<const float2*>(wrow)[k];
    wreg[k] = pack2(w2.x, w2.y);
  }
  const float bias = b_hh[j];

  __shared__ alignas(16) unsigned int h16[64];  // 128 halves: current h
  __shared__ float gh[G3];

  const __half* gp = gi + (size_t)b * T_ * G3;
  float* op = out + (size_t)b * T_ * H_;

  if (j < 64) h16[j] = 0u;               // h0 = 0

  // 2-deep gi prefetch (registers): buf0 = gi[t], buf1 = gi[t+1]
  float ga0 = 0.f, gz0 = 0.f, gn0 = 0.f, ga1 = 0.f, gz1 = 0.f, gn1 = 0.f;
  float hprev = 0.f;
  if (j < H_) {
    ga0 = __half2float(gp[j]);
    gz0 = __half2float(gp[j + 128]);
    gn0 = __half2float(gp[j + 256]);
    ga1 = __half2float(gp[G3 + j]);
    gz1 = __half2float(gp[G3 + j + 128]);
    gn1 = __half2float(gp[G3 + j + 256]);
  }
  __syncthreads();

  for (int t = 0; t < T_; ++t) {
    // issue prefetch for t+2 early (hides HBM latency under matvec+gates)
    float na = 0.f, nz = 0.f, nn = 0.f;
    if (j < H_ && t + 2 < T_) {
      const __half* g2 = gp + (size_t)(t + 2) * G3;
      na = __half2float(g2[j]);
      nz = __half2float(g2[j + 128]);
      nn = __half2float(g2[j + 256]);
    }

    // gh[j] = b_hh[j] + dot(w_hh[j,:], h)
    float a0 = 0.f, a1 = 0.f, a2 = 0.f, a3 = 0.f;
    const uint4* hp = reinterpret_cast<const uint4*>(h16);
#pragma unroll
    for (int k = 0; k < 16; ++k) {
      uint4 hv = hp[k];                  // uniform addr -> broadcast
      a0 = fdot2(wreg[4 * k + 0], hv.x, a0);
      a1 = fdot2(wreg[4 * k + 1], hv.y, a1);
      a2 = fdot2(wreg[4 * k + 2], hv.z, a2);
      a3 = fdot2(wreg[4 * k + 3], hv.w, a3);
    }
    const float ghj = bias + ((a0 + a1) + (a2 + a3));
    gh[j] = ghj;
    __syncthreads();                     // gh visible; all h16 reads done

    if (j < H_) {
      // own ghj IS the r-gate recurrent term (row j of w_hh)
      const float r = fsigmoid(ga0 + ghj);
      const float z = fsigmoid(gz0 + gh[j + 128]);
      const float n = ftanh(gn0 + r * gh[j + 256]);
      const float h = (1.f - z) * n + z * hprev;
      op[(size_t)t * H_ + j] = h;
      hprev = h;
      reinterpret_cast<__half*>(h16)[j] = __float2half(h);
      // rotate prefetch buffers
      ga0 = ga1; gz0 = gz1; gn0 = gn1;
      ga1 = na;  gz1 = nz;  gn1 = nn;
    }
    __syncthreads();                     // h16 update visible for next matvec
  }
}

// ---------------------------------------------------------------------------
// Kernel 3: y = h @ w_proj.T + b_proj, then LayerNorm. In-place on io.
// One wave per block (no barriers needed: wave-lockstep LDS exchange).
// Lane owns output cols lane and lane+64; w_proj rows in registers (f16x2).
// ---------------------------------------------------------------------------
__global__ __launch_bounds__(64, 1) void proj_ln(
    float* __restrict__ io, const float* __restrict__ w_proj,
    const float* __restrict__ b_proj, const float* __restrict__ gamma,
    const float* __restrict__ beta) {
  const int lane = threadIdx.x;
  const int row0 = blockIdx.x * 32;
  const int jA = lane, jB = lane + 64;

  unsigned int wa[64], wb[64];
#pragma unroll
  for (int k = 0; k < 64; ++k) {
    float2 v = reinterpret_cast<const float2*>(w_proj + (size_t)jA * H_)[k];
    wa[k] = pack2(v.x, v.y);
  }
#pragma unroll
  for (int k = 0; k < 64; ++k) {
    float2 v = reinterpret_cast<const float2*>(w_proj + (size_t)jB * H_)[k];
    wb[k] = pack2(v.x, v.y);
  }
  const float bA = b_proj[jA], bB = b_proj[jB];
  const float gmA = gamma[jA], gmB = gamma[jB];
  const float btA = beta[jA], btB = beta[jB];

  __shared__ alignas(16) unsigned int hbuf[64];  // 128 halves: one h row

  for (int r = 0; r < 32; ++r) {
    float* rowp = io + (size_t)(row0 + r) * H_;
    float2 v = reinterpret_cast<float2*>(rowp)[lane];
    hbuf[lane] = pack2(v.x, v.y);
    __syncthreads();  // single wave: cheap; guarantees lgkm visibility

    float aA = bA, aB = bB;
    const uint4* hp = reinterpret_cast<const uint4*>(hbuf);
#pragma unroll
    for (int k = 0; k < 16; ++k) {
      uint4 hv = hp[k];
      aA = fdot2(wa[4 * k + 0], hv.x, aA);
      aA = fdot2(wa[4 * k + 1], hv.y, aA);
      aA = fdot2(wa[4 * k + 2], hv.z, aA);
      aA = fdot2(wa[4 * k + 3], hv.w, aA);
      aB = fdot2(wb[4 * k + 0], hv.x, aB);
      aB = fdot2(wb[4 * k + 1], hv.y, aB);
      aB = fdot2(wb[4 * k + 2], hv.z, aB);
      aB = fdot2(wb[4 * k + 3], hv.w, aB);
    }

    // LayerNorm across 128 cols = 2 values per lane over 64 lanes
    float s = aA + aB;
    float q = aA * aA + aB * aB;
#pragma unroll
    for (int m = 1; m < 64; m <<= 1) {
      s += __shfl_xor(s, m, 64);
      q += __shfl_xor(q, m, 64);
    }
    const float mu = s * (1.f / 128.f);
    const float var = q * (1.f / 128.f) - mu * mu;
    const float rs = rsqrtf(var + 1e-5f);
    rowp[lane]      = (aA - mu) * rs * gmA + btA;
    rowp[lane + 64] = (aB - mu) * rs * gmB + btB;
    __syncthreads();  // hbuf safe to overwrite next row
  }
}

// ---------------------------------------------------------------------------
extern "C" void kernel_launch(void* const* d_in, const int* in_sizes, int n_in,
                              void* d_out, int out_size, void* d_ws, size_t ws_size,
                              hipStream_t stream) {
  const float* x      = (const float*)d_in[0];
  const float* w_ih   = (const float*)d_in[1];
  const float* w_hh   = (const float*)d_in[2];
  const float* b_ih   = (const float*)d_in[3];
  const float* b_hh   = (const float*)d_in[4];
  const float* w_proj = (const float*)d_in[5];
  const float* b_proj = (const float*)d_in[6];
  const float* gamma  = (const float*)d_in[7];
  const float* beta   = (const float*)d_in[8];

  float* out = (float*)d_out;
  __half* gi = (__half*)d_ws;            // 65536*384 f16 = 48 MB scratch

  gi_gemm<<<512, 384, 0, stream>>>(x, w_ih, b_ih, gi);
  gru_scan<<<B_, 384, 0, stream>>>(gi, w_hh, b_hh, out);
  proj_ln<<<(B_ * T_) / 32, 64, 0, stream>>>(out, w_proj, b_proj, gamma, beta);
}